// Round 14
// baseline (120.914 us; speedup 1.0000x reference)
//
#include <hip/hip_runtime.h>
#include <math.h>

// Deepmd angular descriptor, f32 in / f32 out. B=8, N=4096, M=96, OUT_W=384.
//
// R14 vs R13 (~32 us; three neutral scheduling rounds => latency is covered,
// something structural binds): separate the write stream from the read
// stream. The mixed kernel interleaved a 49 MB write with a 63 MB read at
// ~150-cycle grain across all waves -> HBM read/write turnaround; harness
// fills sustain 6.5 TB/s pure-write while our mixed kernel got 2.6 TB/s.
//   dispatch 1: pure zero-fill of out (grid-stride float4, fillBuffer-class)
//   dispatch 2: pure-read compute (R13 minus row store): streams + LDS
//     position gathers + in-register ballot/popc stable rank; rare nonzero
//     items (mean 0.39/pair) scatter 12 B directly into pre-zeroed rows.
//     Owning lane writes its own registers -- no merge, no value shfls.
// Stream order gives fill -> scatter dependency.
#define M_NB   96
#define OUT_W  384
#define NATOM  4096
#define WPB    16
#define NITER  4

struct Pst {               // per-lane stream bundle for one pair
    int    jA, jB;
    float  mkA, mkB;
    float3 oA, oB;
};

struct Gth {               // per-lane gather bundle for one pair
    float4 pi, pjA, pjB;
};

__device__ __forceinline__ void load_pst(Pst& s,
    const int* __restrict__ nb, const float* __restrict__ mk,
    const float* __restrict__ of, long q, int lane, bool low)
{
    const long eA = q * M_NB + lane;
    s.jA  = nb[eA];
    s.mkA = mk[eA];
    s.oA  = *(const float3*)(of + eA * 3);
    if (low) {
        const long eB = eA + 64;
        s.jB  = nb[eB];
        s.mkB = mk[eB];
        s.oB  = *(const float3*)(of + eB * 3);
    } else {
        s.jB = 0; s.mkB = 0.f; s.oB = make_float3(0.f, 0.f, 0.f);
    }
}

__global__ __launch_bounds__(256) void fill_zero_kernel(float4* __restrict__ out4,
                                                        int total4)
{
    const int stride = gridDim.x * 256;
    const float4 z4 = make_float4(0.f, 0.f, 0.f, 0.f);
    #pragma unroll 4
    for (int i = blockIdx.x * 256 + threadIdx.x; i < total4; i += stride)
        out4[i] = z4;
}

__global__ __launch_bounds__(64 * WPB, 8) void deepmd_angular_compute(
    const float* __restrict__ positions,  // [B,N,3]
    const float* __restrict__ cell,       // [B,3,3]
    const float* __restrict__ offsets,    // [B,N,M,3]
    const float* __restrict__ mask,       // [B,N,M]
    const int*   __restrict__ neighbors,  // [B,N,M]
    float*       __restrict__ out,        // [B,N,OUT_W], pre-zeroed
    int N)
{
    __shared__ float4 pos4_s[NATOM];        // 64 KB padded position table

    const int tid  = threadIdx.x;
    const int wv   = tid >> 6;
    const int lane = tid & 63;
    const bool low = lane < 32;

    const int p0 = blockIdx.x * (WPB * NITER);   // first pair of block
    const int b  = p0 / N;                       // uniform (64 | N)

    // ---- stage batch positions -> LDS (padded to 16 B/atom) ----
    {
        const float* pb_ = positions + (size_t)b * N * 3;
        for (int a = tid; a < NATOM; a += 64 * WPB) {
            const float3 v = *(const float3*)(pb_ + 3 * a);
            pos4_s[a] = make_float4(v.x, v.y, v.z, 0.f);
        }
    }
    __syncthreads();                             // only barrier in the kernel

    const float* cb = cell + (size_t)b * 9;      // uniform -> scalar loads
    const float c00 = cb[0], c01 = cb[1], c02 = cb[2];
    const float c10 = cb[3], c11 = cb[4], c12 = cb[5];
    const float c20 = cb[6], c21 = cb[7], c22 = cb[8];

    const long qb = (long)(p0 + wv * NITER);     // this wave's first pair

    // ---- pipeline prologue ----
    Pst s0, s1;
    load_pst(s0, neighbors, mask, offsets, qb + 0, lane, low);
    load_pst(s1, neighbors, mask, offsets, qb + 1, lane, low);
    Gth g0;
    g0.pi  = pos4_s[(int)(qb + 0) - b * N];
    g0.pjA = pos4_s[s0.jA];
    g0.pjB = pos4_s[s0.jB];

    #pragma unroll
    for (int it = 0; it < NITER; ++it) {
        // stage 1: streams for pair it+2
        Pst nxs;
        if (it + 2 < NITER)
            load_pst(nxs, neighbors, mask, offsets, qb + it + 2, lane, low);
        // stage 2: LDS gathers for pair it+1
        Gth g1;
        if (it + 1 < NITER) {
            g1.pi  = pos4_s[(int)(qb + it + 1) - b * N];
            g1.pjA = pos4_s[s1.jA];
            g1.pjB = pos4_s[s1.jB];
        }

        // stage 3: compute pair it
        const int q = (int)qb + it;

        const float dxA = g0.pjA.x - g0.pi.x + s0.oA.x * c00 + s0.oA.y * c10 + s0.oA.z * c20;
        const float dyA = g0.pjA.y - g0.pi.y + s0.oA.x * c01 + s0.oA.y * c11 + s0.oA.z * c21;
        const float dzA = g0.pjA.z - g0.pi.z + s0.oA.x * c02 + s0.oA.y * c12 + s0.oA.z * c22;
        const float dA  = sqrtf(dxA * dxA + dyA * dyA + dzA * dzA + 1e-12f);
        float cutA = 0.f;
        if (s0.mkA != 0.f && dA < 6.f)
            cutA = 0.5f * (__cosf(dA * 0.52359877559829887f) + 1.f) / dA;

        float dxB = 0.f, dyB = 0.f, dzB = 0.f, cutB = 0.f;
        if (low) {
            dxB = g0.pjB.x - g0.pi.x + s0.oB.x * c00 + s0.oB.y * c10 + s0.oB.z * c20;
            dyB = g0.pjB.y - g0.pi.y + s0.oB.x * c01 + s0.oB.y * c11 + s0.oB.z * c21;
            dzB = g0.pjB.z - g0.pi.z + s0.oB.x * c02 + s0.oB.y * c12 + s0.oB.z * c22;
            const float dB = sqrtf(dxB * dxB + dyB * dyB + dzB * dzB + 1e-12f);
            if (s0.mkB != 0.f && dB < 6.f)
                cutB = 0.5f * (__cosf(dB * 0.52359877559829887f) + 1.f) / dB;
        }

        // ---- rare path: in-register stable rank + direct 12 B scatter ----
        // rank(m) = #{k: cut_k > cut_m} + #{k<m: cut_k == cut_m}
        float* rowp = out + (size_t)q * OUT_W;

        unsigned long long t = __ballot(cutA != 0.f);
        while (t) {
            const int s = (int)__builtin_ctzll(t); t &= t - 1;   // item m = s
            const float c = __shfl(cutA, s);
            const unsigned long long gtA = __ballot(cutA > c);
            const unsigned long long gtB = __ballot(cutB > c);
            const unsigned long long eqA = __ballot(cutA == c);
            const int rank = __popcll(gtA) + __popcll(gtB)
                           + __popcll(eqA & ((1ull << s) - 1ull));
            if (lane == s) {                     // owner writes own registers
                rowp[3 * rank + 0] = cutA * dxA;
                rowp[3 * rank + 1] = cutA * dyA;
                rowp[3 * rank + 2] = cutA * dzA;
            }
        }
        t = __ballot(cutB != 0.f);
        while (t) {
            const int s = (int)__builtin_ctzll(t); t &= t - 1;   // item m = 64+s
            const float c = __shfl(cutB, s);
            const unsigned long long gtA = __ballot(cutA > c);
            const unsigned long long gtB = __ballot(cutB > c);
            const unsigned long long eqA = __ballot(cutA == c);  // all k<64 < m
            const unsigned long long eqB = __ballot(cutB == c);
            const int rank = __popcll(gtA) + __popcll(gtB) + __popcll(eqA)
                           + __popcll(eqB & ((1ull << s) - 1ull));
            if (lane == s) {                     // cutB owner is low lane s
                rowp[3 * rank + 0] = cutB * dxB;
                rowp[3 * rank + 1] = cutB * dyB;
                rowp[3 * rank + 2] = cutB * dzB;
            }
        }

        // rotate pipeline
        s0 = s1; s1 = nxs; g0 = g1;
    }
}

extern "C" void kernel_launch(void* const* d_in, const int* in_sizes, int n_in,
                              void* d_out, int out_size, void* d_ws, size_t ws_size,
                              hipStream_t stream) {
    const float* positions = (const float*)d_in[0];
    const float* cell      = (const float*)d_in[1];
    const float* offsets   = (const float*)d_in[2];
    const float* mask      = (const float*)d_in[3];
    const int*   neighbors = (const int*)d_in[4];
    float*       out       = (float*)d_out;

    const int BN = in_sizes[0] / 3;        // B*N = 32768
    const int B  = in_sizes[1] / 9;        // 8
    const int N  = BN / B;                 // 4096

    // 1) pure write stream: zero-fill out (49 MB @ ~6.4 TB/s)
    fill_zero_kernel<<<2048, 256, 0, stream>>>((float4*)out, out_size / 4);

    // 2) pure read stream + rare scatter
    dim3 block(64 * WPB, 1, 1);            // 1024 threads = 16 waves
    dim3 grid(BN / (WPB * NITER), 1, 1);   // 512 blocks = 2/CU resident
    deepmd_angular_compute<<<grid, block, 0, stream>>>(
        positions, cell, offsets, mask, neighbors, out, N);
}

// Round 15
// 115.313 us; speedup vs baseline: 1.0486x; 1.0486x over previous
//
#include <hip/hip_runtime.h>
#include <math.h>

// Deepmd angular descriptor, f32 in / f32 out. B=8, N=4096, M=96, OUT_W=384.
//
// R15 vs R13/R14 (~31 us monolithic; split proved read side alone = ~27 us
// at 2.3 TB/s): all-dense load shape. Each wave owns 2 consecutive pairs =
// 192 contiguous stream elements = exactly 3 per lane, so every global load
// is a full-wave dense dword/dwordx3 -- no exec-masked half-wave loads, no
// odd 96-wide mapping. Item map: i0: e=base+lane (pair0 m=lane);
// i1: e=base+64+lane (lane<32: pair0 m=64+lane; else pair1 m=lane-32);
// i2: e=base+128+lane (pair1 m=32+lane). Ballot-rank per pair with LOW/HIGH
// masks; ranks distinct per pair; register merge; one b128+b64 store per row.
// LDS = 64 KB float4 position table; single __syncthreads.
#define M_NB   96
#define OUT_W  384
#define NATOM  4096
#define WPB    16
#define LOWM   0x00000000FFFFFFFFull
#define HIGHM  0xFFFFFFFF00000000ull

// fold one item (row floats [base,base+3)) into this lane's output slots:
// float4 owns [4*lane,4*lane+4), float2 owns [256+2*lane,256+2*lane+2)
__device__ __forceinline__ void merge3(float4& a4, float2& a2, int base,
                                       float v0, float v1, float v2, int lane)
{
    const int f4lo = 4 * lane;
    const int f2lo = 256 + 2 * lane;
    const float v[3] = {v0, v1, v2};
    #pragma unroll
    for (int t = 0; t < 3; ++t) {
        const int idx = base + t;
        if      (idx == f4lo)     a4.x = v[t];
        else if (idx == f4lo + 1) a4.y = v[t];
        else if (idx == f4lo + 2) a4.z = v[t];
        else if (idx == f4lo + 3) a4.w = v[t];
        else if (idx == f2lo)     a2.x = v[t];
        else if (idx == f2lo + 1) a2.y = v[t];
    }
}

__global__ __launch_bounds__(64 * WPB, 8) void deepmd_angular_kernel(
    const float* __restrict__ positions,  // [B,N,3]
    const float* __restrict__ cell,       // [B,3,3]
    const float* __restrict__ offsets,    // [B,N,M,3]
    const float* __restrict__ mask,       // [B,N,M]
    const int*   __restrict__ neighbors,  // [B,N,M]
    float*       __restrict__ out,        // [B,N,OUT_W]
    int N)
{
    __shared__ float4 pos4_s[NATOM];        // 64 KB padded position table

    const int tid  = threadIdx.x;
    const int wv   = tid >> 6;
    const int lane = tid & 63;

    const int p0 = blockIdx.x * (WPB * 4);       // 64 pairs per block
    const int b  = p0 / N;                       // uniform (64 | N)

    // ---- stage batch positions -> LDS (padded to 16 B/atom) ----
    {
        const float* pb_ = positions + (size_t)b * N * 3;
        for (int a = tid; a < NATOM; a += 64 * WPB) {
            const float3 v = *(const float3*)(pb_ + 3 * a);
            pos4_s[a] = make_float4(v.x, v.y, v.z, 0.f);
        }
    }
    __syncthreads();                             // only barrier in the kernel

    const float* cb = cell + (size_t)b * 9;      // uniform -> scalar loads
    const float c00 = cb[0], c01 = cb[1], c02 = cb[2];
    const float c10 = cb[3], c11 = cb[4], c12 = cb[5];
    const float c20 = cb[6], c21 = cb[7], c22 = cb[8];

    #pragma unroll
    for (int it = 0; it < 2; ++it) {
        const int q0   = p0 + wv * 4 + it * 2;   // first of this wave's 2 pairs
        const long base = (long)q0 * M_NB;       // contiguous 192 elements
        const long e0 = base + lane, e1 = e0 + 64, e2 = e0 + 128;

        // ---- dense full-wave stream loads (3 items/lane) ----
        const int   j0 = neighbors[e0], j1 = neighbors[e1], j2 = neighbors[e2];
        const float m0 = mask[e0],      m1 = mask[e1],      m2 = mask[e2];
        const float3 o0 = *(const float3*)(offsets + e0 * 3);
        const float3 o1 = *(const float3*)(offsets + e1 * 3);
        const float3 o2 = *(const float3*)(offsets + e2 * 3);

        // ---- LDS gathers ----
        const int nn0 = q0 - b * N;
        const float4 pi0 = pos4_s[nn0];          // uniform broadcasts
        const float4 pi1 = pos4_s[nn0 + 1];
        const float4 pj0 = pos4_s[j0];
        const float4 pj1 = pos4_s[j1];
        const float4 pj2 = pos4_s[j2];
        const float4 pa  = (lane < 32) ? pi0 : pi1;   // item1's own atom

        // ---- cut per item (w = cut * dis_vec stored in-place) ----
        float w0x = pj0.x - pi0.x + o0.x * c00 + o0.y * c10 + o0.z * c20;
        float w0y = pj0.y - pi0.y + o0.x * c01 + o0.y * c11 + o0.z * c21;
        float w0z = pj0.z - pi0.z + o0.x * c02 + o0.y * c12 + o0.z * c22;
        float d   = sqrtf(w0x * w0x + w0y * w0y + w0z * w0z + 1e-12f);
        float c0v = 0.f;
        if (m0 != 0.f && d < 6.f)
            c0v = 0.5f * (__cosf(d * 0.52359877559829887f) + 1.f) / d;
        w0x *= c0v; w0y *= c0v; w0z *= c0v;

        float w1x = pj1.x - pa.x + o1.x * c00 + o1.y * c10 + o1.z * c20;
        float w1y = pj1.y - pa.y + o1.x * c01 + o1.y * c11 + o1.z * c21;
        float w1z = pj1.z - pa.z + o1.x * c02 + o1.y * c12 + o1.z * c22;
        d = sqrtf(w1x * w1x + w1y * w1y + w1z * w1z + 1e-12f);
        float c1v = 0.f;
        if (m1 != 0.f && d < 6.f)
            c1v = 0.5f * (__cosf(d * 0.52359877559829887f) + 1.f) / d;
        w1x *= c1v; w1y *= c1v; w1z *= c1v;

        float w2x = pj2.x - pi1.x + o2.x * c00 + o2.y * c10 + o2.z * c20;
        float w2y = pj2.y - pi1.y + o2.x * c01 + o2.y * c11 + o2.z * c21;
        float w2z = pj2.z - pi1.z + o2.x * c02 + o2.y * c12 + o2.z * c22;
        d = sqrtf(w2x * w2x + w2y * w2y + w2z * w2z + 1e-12f);
        float c2v = 0.f;
        if (m2 != 0.f && d < 6.f)
            c2v = 0.5f * (__cosf(d * 0.52359877559829887f) + 1.f) / d;
        w2x *= c2v; w2y *= c2v; w2z *= c2v;

        // ---- pair0: rank + register merge ----
        // rank(m) = #{k: cut_k > cut_m} + #{k<m: cut_k == cut_m}
        float4 a4 = make_float4(0.f, 0.f, 0.f, 0.f);
        float2 a2 = make_float2(0.f, 0.f);
        unsigned long long t = __ballot(c0v != 0.f);
        while (t) {                                  // item m = s (c0 owner)
            const int s = (int)__builtin_ctzll(t); t &= t - 1;
            const float c = __shfl(c0v, s);
            const int rank = __popcll(__ballot(c0v > c))
                           + __popcll(__ballot(c1v > c) & LOWM)
                           + __popcll(__ballot(c0v == c) & ((1ull << s) - 1ull));
            merge3(a4, a2, 3 * rank,
                   __shfl(w0x, s), __shfl(w0y, s), __shfl(w0z, s), lane);
        }
        t = __ballot(c1v != 0.f) & LOWM;
        while (t) {                                  // item m = 64+s (c1 low)
            const int s = (int)__builtin_ctzll(t); t &= t - 1;
            const float c = __shfl(c1v, s);
            const int rank = __popcll(__ballot(c0v > c))
                           + __popcll(__ballot(c1v > c) & LOWM)
                           + __popcll(__ballot(c0v == c))
                           + __popcll(__ballot(c1v == c) & LOWM & ((1ull << s) - 1ull));
            merge3(a4, a2, 3 * rank,
                   __shfl(w1x, s), __shfl(w1y, s), __shfl(w1z, s), lane);
        }
        float* row0 = out + (size_t)q0 * OUT_W;
        ((float4*)row0)[lane] = a4;
        ((float2*)(row0 + 256))[lane] = a2;

        // ---- pair1: rank + register merge ----
        float4 b4 = make_float4(0.f, 0.f, 0.f, 0.f);
        float2 b2 = make_float2(0.f, 0.f);
        t = __ballot(c1v != 0.f) & HIGHM;
        while (t) {                                  // item m = s-32 (c1 high)
            const int s = (int)__builtin_ctzll(t); t &= t - 1;
            const float c = __shfl(c1v, s);
            const int rank = __popcll(__ballot(c1v > c) & HIGHM)
                           + __popcll(__ballot(c2v > c))
                           + __popcll(__ballot(c1v == c) & HIGHM & ((1ull << s) - 1ull));
            merge3(b4, b2, 3 * rank,
                   __shfl(w1x, s), __shfl(w1y, s), __shfl(w1z, s), lane);
        }
        t = __ballot(c2v != 0.f);
        while (t) {                                  // item m = 32+s (c2 owner)
            const int s = (int)__builtin_ctzll(t); t &= t - 1;
            const float c = __shfl(c2v, s);
            const int rank = __popcll(__ballot(c1v > c) & HIGHM)
                           + __popcll(__ballot(c2v > c))
                           + __popcll(__ballot(c1v == c) & HIGHM)
                           + __popcll(__ballot(c2v == c) & ((1ull << s) - 1ull));
            merge3(b4, b2, 3 * rank,
                   __shfl(w2x, s), __shfl(w2y, s), __shfl(w2z, s), lane);
        }
        float* row1 = out + (size_t)(q0 + 1) * OUT_W;
        ((float4*)row1)[lane] = b4;
        ((float2*)(row1 + 256))[lane] = b2;
    }
}

extern "C" void kernel_launch(void* const* d_in, const int* in_sizes, int n_in,
                              void* d_out, int out_size, void* d_ws, size_t ws_size,
                              hipStream_t stream) {
    const float* positions = (const float*)d_in[0];
    const float* cell      = (const float*)d_in[1];
    const float* offsets   = (const float*)d_in[2];
    const float* mask      = (const float*)d_in[3];
    const int*   neighbors = (const int*)d_in[4];
    float*       out       = (float*)d_out;

    const int BN = in_sizes[0] / 3;        // B*N = 32768
    const int B  = in_sizes[1] / 9;        // 8
    const int N  = BN / B;                 // 4096

    dim3 block(64 * WPB, 1, 1);            // 1024 threads = 16 waves
    dim3 grid(BN / (WPB * 4), 1, 1);       // 512 blocks = 2/CU resident
    deepmd_angular_kernel<<<grid, block, 0, stream>>>(
        positions, cell, offsets, mask, neighbors, out, N);
}